// Round 1
// baseline (1302.619 us; speedup 1.0000x reference)
//
#include <hip/hip_runtime.h>

#define NN      100000
#define NUSERS  50000
#define NE      1250000
#define DIM     64
#define BN_EPS  1e-5f

// ---------------------------------------------------------------------------
// deg[v] += 1 for every edge destination (self-loop added in dinv_kernel)
__global__ __launch_bounds__(256) void deg_kernel(const int* __restrict__ ei,
                                                  float* __restrict__ deg) {
    int stride = gridDim.x * blockDim.x;
    for (int e = blockIdx.x * blockDim.x + threadIdx.x; e < NE; e += stride) {
        int d = ei[NE + e];
        atomicAdd(&deg[d], 1.0f);
    }
}

// dinv[v] = rsqrt(deg[v] + 1)  (in-place over deg; +1 = self-loop)
__global__ __launch_bounds__(256) void dinv_kernel(float* __restrict__ deg) {
    int v = blockIdx.x * blockDim.x + threadIdx.x;
    if (v < NN) deg[v] = rsqrtf(deg[v] + 1.0f);
}

// ---------------------------------------------------------------------------
// g[v][:] = dinv[v] * (xin[v][:] @ W^T)   where xin is optionally the previous
// layer's un-finalized acc: x = dinv[v]*X[v] + bprev.
// Writes g to G and also initializes ACC = g (the self-loop term).
// One wave per row; lane j computes output column j.
__global__ __launch_bounds__(256) void gemm_scale(const float* __restrict__ X,
                                                  const float* __restrict__ W,
                                                  const float* __restrict__ dinv,
                                                  const float* __restrict__ bprev,
                                                  float* __restrict__ G,
                                                  float* __restrict__ ACC,
                                                  int apply_prev) {
    __shared__ float WT[64 * 64];  // WT[k*64+j] = W[j*64+k]
    for (int i = threadIdx.x; i < 64 * 64; i += blockDim.x) {
        int j = i >> 6, k = i & 63;
        WT[k * 64 + j] = W[i];
    }
    __syncthreads();

    int lane = threadIdx.x & 63;
    float bp = apply_prev ? bprev[lane] : 0.0f;

    int wid = (blockIdx.x * blockDim.x + threadIdx.x) >> 6;
    int nw  = (gridDim.x * blockDim.x) >> 6;
    for (int v = wid; v < NN; v += nw) {
        float dv = dinv[v];
        float xr = X[v * 64 + lane];
        if (apply_prev) xr = dv * xr + bp;
        float acc = 0.0f;
#pragma unroll
        for (int k = 0; k < 64; ++k) {
            float xk = __shfl(xr, k, 64);
            acc += xk * WT[k * 64 + lane];  // banks = lane%32 -> 2-way, free
        }
        float g = dv * acc;
        G[v * 64 + lane]   = g;
        ACC[v * 64 + lane] = g;  // self-loop init (safe: reg xr read pre-write)
    }
}

// ---------------------------------------------------------------------------
// One wave per edge: ACC[dst][:] += G[src][:]
__global__ __launch_bounds__(256) void scatter_kernel(const int* __restrict__ ei,
                                                      const float* __restrict__ G,
                                                      float* __restrict__ ACC) {
    int lane = threadIdx.x & 63;
    int wid  = (blockIdx.x * blockDim.x + threadIdx.x) >> 6;
    int nw   = (gridDim.x * blockDim.x) >> 6;
    for (int e = wid; e < NE; e += nw) {
        int s = ei[e];
        int d = ei[NE + e];
        float val = G[s * 64 + lane];
        atomicAdd(&ACC[d * 64 + lane], val);
    }
}

// ---------------------------------------------------------------------------
// Column-wise sum / sum-of-squares of y = dinv[v]*ACC[v][j] + blast[j]
__global__ __launch_bounds__(256) void bn_stats(const float* __restrict__ ACC,
                                                const float* __restrict__ dinv,
                                                const float* __restrict__ blast,
                                                float* __restrict__ sums) {
    int j = threadIdx.x & 63;
    float b = blast[j];
    int wid = (blockIdx.x * blockDim.x + threadIdx.x) >> 6;
    int nw  = (gridDim.x * blockDim.x) >> 6;
    float s = 0.0f, s2 = 0.0f;
    for (int v = wid; v < NN; v += nw) {
        float y = dinv[v] * ACC[v * 64 + j] + b;
        s += y;
        s2 += y * y;
    }
    __shared__ float ls[256], ls2[256];
    ls[threadIdx.x] = s;
    ls2[threadIdx.x] = s2;
    __syncthreads();
    if (threadIdx.x < 64) {
        s  = ls[threadIdx.x] + ls[threadIdx.x + 64] + ls[threadIdx.x + 128] + ls[threadIdx.x + 192];
        s2 = ls2[threadIdx.x] + ls2[threadIdx.x + 64] + ls2[threadIdx.x + 128] + ls2[threadIdx.x + 192];
        atomicAdd(&sums[j], s);
        atomicAdd(&sums[64 + j], s2);
    }
}

// out = (y - mean) * rsqrt(var + eps) * gamma + beta
__global__ __launch_bounds__(256) void bn_apply(const float* __restrict__ ACC,
                                                const float* __restrict__ dinv,
                                                const float* __restrict__ blast,
                                                const float* __restrict__ sums,
                                                const float* __restrict__ gamma,
                                                const float* __restrict__ beta,
                                                float* __restrict__ out) {
    const float invN = 1.0f / (float)NN;
    int stride = gridDim.x * blockDim.x;
    for (int i = blockIdx.x * blockDim.x + threadIdx.x; i < NN * 64; i += stride) {
        int j = i & 63;
        int v = i >> 6;
        float mean = sums[j] * invN;
        float var  = sums[64 + j] * invN - mean * mean;
        float y = dinv[v] * ACC[i] + blast[j];
        out[i] = (y - mean) * rsqrtf(var + BN_EPS) * gamma[j] + beta[j];
    }
}

// ---------------------------------------------------------------------------
extern "C" void kernel_launch(void* const* d_in, const int* in_sizes, int n_in,
                              void* d_out, int out_size, void* d_ws, size_t ws_size,
                              hipStream_t stream) {
    const float* x     = (const float*)d_in[0];
    const int*   ei    = (const int*)d_in[1];
    const float* Ws    = (const float*)d_in[2];
    const float* bs    = (const float*)d_in[3];
    const float* gamma = (const float*)d_in[4];
    const float* beta  = (const float*)d_in[5];
    float* out = (float*)d_out;

    char* ws = (char*)d_ws;
    float* P    = (float*)ws;                              // NN*64 acc buffer
    float* dinv = (float*)(ws + (size_t)NN * 64 * 4);      // NN floats (deg -> dinv)
    float* sums = dinv + NN;                               // 128 floats

    hipMemsetAsync(dinv, 0, NN * sizeof(float), stream);
    hipMemsetAsync(sums, 0, 128 * sizeof(float), stream);

    deg_kernel<<<2048, 256, 0, stream>>>(ei, dinv);
    dinv_kernel<<<(NN + 255) / 256, 256, 0, stream>>>(dinv);

    for (int l = 0; l < 3; ++l) {
        const float* Xin   = (l == 0) ? x : P;
        const float* bprev = (l == 0) ? nullptr : (bs + (l - 1) * 64);
        gemm_scale<<<4096, 256, 0, stream>>>(Xin, Ws + l * 64 * 64, dinv, bprev,
                                             out /*G*/, P /*ACC*/, l > 0);
        scatter_kernel<<<8192, 256, 0, stream>>>(ei, out /*G*/, P /*ACC*/);
    }

    bn_stats<<<2048, 256, 0, stream>>>(P, dinv, bs + 128, sums);
    bn_apply<<<2048, 256, 0, stream>>>(P, dinv, bs + 128, sums, gamma, beta, out);
}

// Round 2
// 836.752 us; speedup vs baseline: 1.5568x; 1.5568x over previous
//
#include <hip/hip_runtime.h>

#define NN      100000
#define NUSERS  50000
#define NE      1250000
#define DIM     64
#define BN_EPS  1e-5f
#define NBLK    391   // ceil(NN / 256)

// ---------------------------------------------------------------------------
// Integer degree count over edge destinations.
__global__ __launch_bounds__(256) void deg_int_kernel(const int* __restrict__ ei,
                                                      int* __restrict__ degi) {
    int stride = gridDim.x * blockDim.x;
    for (int e = blockIdx.x * blockDim.x + threadIdx.x; e < NE; e += stride) {
        atomicAdd(&degi[ei[NE + e]], 1);
    }
}

// dinv[v] = rsqrt(deg[v] + 1)   (+1 = self-loop)
__global__ __launch_bounds__(256) void dinv_kernel(const int* __restrict__ degi,
                                                   float* __restrict__ dinv) {
    int v = blockIdx.x * blockDim.x + threadIdx.x;
    if (v < NN) dinv[v] = rsqrtf((float)degi[v] + 1.0f);
}

// ---------------------------------------------------------------------------
// Exclusive scan of degi -> row_start, in three passes.
// Pass 1: per-block (256 elems) sums.
__global__ __launch_bounds__(256) void scan_block_sums(const int* __restrict__ degi,
                                                       int* __restrict__ bsum) {
    __shared__ int ls[256];
    int v = blockIdx.x * 256 + threadIdx.x;
    int d = (v < NN) ? degi[v] : 0;
    ls[threadIdx.x] = d;
    __syncthreads();
    for (int off = 128; off > 0; off >>= 1) {
        if (threadIdx.x < off) ls[threadIdx.x] += ls[threadIdx.x + off];
        __syncthreads();
    }
    if (threadIdx.x == 0) bsum[blockIdx.x] = ls[0];
}

// Pass 2: exclusive scan of the NBLK block sums (single block, 512 threads).
__global__ __launch_bounds__(512) void scan_bsums(const int* __restrict__ bsum,
                                                  int* __restrict__ boff) {
    __shared__ int ls[512];
    int tid = threadIdx.x;
    int val = (tid < NBLK) ? bsum[tid] : 0;
    ls[tid] = val;
    __syncthreads();
    for (int off = 1; off < 512; off <<= 1) {
        int t = (tid >= off) ? ls[tid - off] : 0;
        __syncthreads();
        ls[tid] += t;
        __syncthreads();
    }
    if (tid < NBLK) boff[tid] = ls[tid] - val;  // exclusive
}

// Pass 3: intra-block exclusive scan + block offset -> row_start, cursor.
__global__ __launch_bounds__(256) void scan_final(const int* __restrict__ degi,
                                                  const int* __restrict__ boff,
                                                  int* __restrict__ row_start,
                                                  int* __restrict__ cursor) {
    __shared__ int ls[256];
    int b = blockIdx.x, tid = threadIdx.x;
    int v = b * 256 + tid;
    int d = (v < NN) ? degi[v] : 0;
    ls[tid] = d;
    __syncthreads();
    for (int off = 1; off < 256; off <<= 1) {
        int t = (tid >= off) ? ls[tid - off] : 0;
        __syncthreads();
        ls[tid] += t;
        __syncthreads();
    }
    int rs = boff[b] + ls[tid] - d;  // exclusive
    if (v < NN) {
        row_start[v] = rs;
        cursor[v]    = rs;
    }
    if (b == 0 && tid == 0) row_start[NN] = NE;
}

// Placement: csr_src[cursor[dst]++] = src
__global__ __launch_bounds__(256) void place_edges(const int* __restrict__ ei,
                                                   int* __restrict__ cursor,
                                                   int* __restrict__ csr_src) {
    int stride = gridDim.x * blockDim.x;
    for (int e = blockIdx.x * blockDim.x + threadIdx.x; e < NE; e += stride) {
        int s = ei[e];
        int d = ei[NE + e];
        int pos = atomicAdd(&cursor[d], 1);
        csr_src[pos] = s;
    }
}

// ---------------------------------------------------------------------------
// g[v][:] = dinv[v] * (xin[v][:] @ W^T), xin optionally = dinv[v]*X[v] + bprev
// (previous layer finalize folded in). One wave per row, lane j = output col j.
__global__ __launch_bounds__(256) void gemm_scale(const float* __restrict__ X,
                                                  const float* __restrict__ W,
                                                  const float* __restrict__ dinv,
                                                  const float* __restrict__ bprev,
                                                  float* __restrict__ G,
                                                  int apply_prev) {
    __shared__ float WT[64 * 64];  // WT[k*64+j] = W[j*64+k]
    for (int i = threadIdx.x; i < 64 * 64; i += blockDim.x) {
        int j = i >> 6, k = i & 63;
        WT[k * 64 + j] = W[i];
    }
    __syncthreads();

    int lane = threadIdx.x & 63;
    float bp = apply_prev ? bprev[lane] : 0.0f;

    int wid = (blockIdx.x * blockDim.x + threadIdx.x) >> 6;
    int nw  = (gridDim.x * blockDim.x) >> 6;
    for (int v = wid; v < NN; v += nw) {
        float dv = dinv[v];
        float xr = X[v * 64 + lane];
        if (apply_prev) xr = dv * xr + bp;
        float acc = 0.0f;
#pragma unroll
        for (int k = 0; k < 64; ++k) {
            float xk = __shfl(xr, k, 64);
            acc += xk * WT[k * 64 + lane];
        }
        G[v * 64 + lane] = dv * acc;
    }
}

// ---------------------------------------------------------------------------
// Atomic-free aggregation: one wave per dst row.
// ACC[v][:] = G[v][:] (self-loop) + sum over in-edges of G[src][:]
__global__ __launch_bounds__(256) void gather_kernel(const int* __restrict__ row_start,
                                                     const int* __restrict__ csr_src,
                                                     const float* __restrict__ G,
                                                     float* __restrict__ ACC) {
    int lane = threadIdx.x & 63;
    int wid  = (blockIdx.x * blockDim.x + threadIdx.x) >> 6;
    int nw   = (gridDim.x * blockDim.x) >> 6;
    for (int v = wid; v < NN; v += nw) {
        int rs = row_start[v];
        int re = row_start[v + 1];
        float acc = G[v * 64 + lane];  // self-loop
        for (int base = rs; base < re; base += 64) {
            int n = re - base;
            if (n > 64) n = 64;
            int myidx = (lane < n) ? csr_src[base + lane] : 0;
#pragma unroll 4
            for (int t = 0; t < n; ++t) {
                int s = __shfl(myidx, t, 64);
                acc += G[(size_t)s * 64 + lane];
            }
        }
        ACC[v * 64 + lane] = acc;
    }
}

// ---------------------------------------------------------------------------
// Column-wise sum / sum-of-squares of y = dinv[v]*ACC[v][j] + blast[j]
__global__ __launch_bounds__(256) void bn_stats(const float* __restrict__ ACC,
                                                const float* __restrict__ dinv,
                                                const float* __restrict__ blast,
                                                float* __restrict__ sums) {
    int j = threadIdx.x & 63;
    float b = blast[j];
    int wid = (blockIdx.x * blockDim.x + threadIdx.x) >> 6;
    int nw  = (gridDim.x * blockDim.x) >> 6;
    float s = 0.0f, s2 = 0.0f;
    for (int v = wid; v < NN; v += nw) {
        float y = dinv[v] * ACC[v * 64 + j] + b;
        s += y;
        s2 += y * y;
    }
    __shared__ float ls[256], ls2[256];
    ls[threadIdx.x] = s;
    ls2[threadIdx.x] = s2;
    __syncthreads();
    if (threadIdx.x < 64) {
        s  = ls[threadIdx.x] + ls[threadIdx.x + 64] + ls[threadIdx.x + 128] + ls[threadIdx.x + 192];
        s2 = ls2[threadIdx.x] + ls2[threadIdx.x + 64] + ls2[threadIdx.x + 128] + ls2[threadIdx.x + 192];
        atomicAdd(&sums[j], s);
        atomicAdd(&sums[64 + j], s2);
    }
}

// out = (y - mean) * rsqrt(var + eps) * gamma + beta
__global__ __launch_bounds__(256) void bn_apply(const float* __restrict__ ACC,
                                                const float* __restrict__ dinv,
                                                const float* __restrict__ blast,
                                                const float* __restrict__ sums,
                                                const float* __restrict__ gamma,
                                                const float* __restrict__ beta,
                                                float* __restrict__ out) {
    const float invN = 1.0f / (float)NN;
    int stride = gridDim.x * blockDim.x;
    for (int i = blockIdx.x * blockDim.x + threadIdx.x; i < NN * 64; i += stride) {
        int j = i & 63;
        int v = i >> 6;
        float mean = sums[j] * invN;
        float var  = sums[64 + j] * invN - mean * mean;
        float y = dinv[v] * ACC[i] + blast[j];
        out[i] = (y - mean) * rsqrtf(var + BN_EPS) * gamma[j] + beta[j];
    }
}

// ---------------------------------------------------------------------------
extern "C" void kernel_launch(void* const* d_in, const int* in_sizes, int n_in,
                              void* d_out, int out_size, void* d_ws, size_t ws_size,
                              hipStream_t stream) {
    const float* x     = (const float*)d_in[0];
    const int*   ei    = (const int*)d_in[1];
    const float* Ws    = (const float*)d_in[2];
    const float* bs    = (const float*)d_in[3];
    const float* gamma = (const float*)d_in[4];
    const float* beta  = (const float*)d_in[5];
    float* out = (float*)d_out;

    char* ws = (char*)d_ws;
    size_t off = 0;
    float* P         = (float*)(ws + off); off += (size_t)NN * 64 * 4;   // ACC
    float* dinv      = (float*)(ws + off); off += (size_t)NN * 4;
    float* sums      = (float*)(ws + off); off += 128 * 4;
    int*   degi      = (int*)(ws + off);   off += (size_t)NN * 4;
    int*   row_start = (int*)(ws + off);   off += (size_t)(NN + 1) * 4;
    int*   cursor    = (int*)(ws + off);   off += (size_t)NN * 4;
    int*   bsum      = (int*)(ws + off);   off += 512 * 4;
    int*   boff      = (int*)(ws + off);   off += 512 * 4;
    int*   csr_src   = (int*)(ws + off);   off += (size_t)NE * 4;

    hipMemsetAsync(degi, 0, NN * sizeof(int), stream);
    hipMemsetAsync(sums, 0, 128 * sizeof(float), stream);

    // --- CSR build (once per call) ---
    deg_int_kernel<<<2048, 256, 0, stream>>>(ei, degi);
    dinv_kernel<<<(NN + 255) / 256, 256, 0, stream>>>(degi, dinv);
    scan_block_sums<<<NBLK, 256, 0, stream>>>(degi, bsum);
    scan_bsums<<<1, 512, 0, stream>>>(bsum, boff);
    scan_final<<<NBLK, 256, 0, stream>>>(degi, boff, row_start, cursor);
    place_edges<<<2048, 256, 0, stream>>>(ei, cursor, csr_src);

    // --- 3 GCN layers: transform+scale, then atomic-free gather ---
    for (int l = 0; l < 3; ++l) {
        const float* Xin   = (l == 0) ? x : P;
        const float* bprev = (l == 0) ? nullptr : (bs + (l - 1) * 64);
        gemm_scale<<<4096, 256, 0, stream>>>(Xin, Ws + l * 64 * 64, dinv, bprev,
                                             out /*G*/, l > 0);
        gather_kernel<<<2048, 256, 0, stream>>>(row_start, csr_src, out /*G*/, P /*ACC*/);
    }

    // --- BatchNorm over nodes ---
    bn_stats<<<2048, 256, 0, stream>>>(P, dinv, bs + 128, sums);
    bn_apply<<<2048, 256, 0, stream>>>(P, dinv, bs + 128, sums, gamma, beta, out);
}

// Round 3
// 581.216 us; speedup vs baseline: 2.2412x; 1.4397x over previous
//
#include <hip/hip_runtime.h>

#define NN      100000
#define NUSERS  50000
#define NE      1250000
#define DIM     64
#define BN_EPS  1e-5f
#define NBLK    391   // ceil(NN / 256)
#define NBUCK   16
#define NCHUNK  48    // blocks per bucket for partitioned edge scans

typedef __attribute__((ext_vector_type(8))) short s16x8;
typedef __attribute__((ext_vector_type(4))) float f32x4;

__device__ __forceinline__ short f2b(float f) {  // fp32 -> bf16 RNE
    unsigned u = __builtin_bit_cast(unsigned, f);
    u = (u + 0x7fffu + ((u >> 16) & 1u)) >> 16;
    return (short)u;
}
__device__ __forceinline__ float b2f(unsigned short s) {
    unsigned u = ((unsigned)s) << 16;
    return __builtin_bit_cast(float, u);
}
__device__ __forceinline__ int bucket_of(int d) {  // floor(d/6250), exact for d<100000
    return (int)(((unsigned long long)(unsigned)d * 687195ull) >> 32);
}

// ---------------------------------------------------------------------------
// Partitioned degree count: block handles bucket blockIdx%16 (XCD-local lines),
// wave-private LDS queue densifies the 1/16-sparse kept lanes.
__global__ __launch_bounds__(256) void deg_part(const int* __restrict__ ei,
                                                int* __restrict__ degi) {
    __shared__ int Qd[4][128];
    int lane = threadIdx.x & 63, wave = threadIdx.x >> 6;
    int B = blockIdx.x & (NBUCK - 1);
    int gw = (blockIdx.x >> 4) * 4 + wave;           // wave id within bucket
    const int NW  = NCHUNK * 4;
    const int per = (NE + NW - 1) / NW;
    int e0 = gw * per;
    int e1 = e0 + per; if (e1 > NE) e1 = NE;
    int qn = 0;
    for (int e = e0 + lane; e - lane < e1; e += 64) {
        bool keep = false; int d = 0;
        if (e < e1) { d = ei[NE + e]; keep = (bucket_of(d) == B); }
        unsigned long long m = __ballot(keep);
        if (keep) {
            int rank = __popcll(m & ((1ull << lane) - 1ull));
            Qd[wave][qn + rank] = d;
        }
        qn += __popcll(m);
        if (qn >= 64) {
            int dd = Qd[wave][lane];
            atomicAdd(&degi[dd], 1);
            qn -= 64;
            int mv = (lane < qn) ? Qd[wave][64 + lane] : 0;
            if (lane < qn) Qd[wave][lane] = mv;
        }
    }
    if (lane < qn) atomicAdd(&degi[Qd[wave][lane]], 1);
}

// dinv[v] = rsqrt(deg[v] + 1)   (+1 = self-loop)
__global__ __launch_bounds__(256) void dinv_kernel(const int* __restrict__ degi,
                                                   float* __restrict__ dinv) {
    int v = blockIdx.x * blockDim.x + threadIdx.x;
    if (v < NN) dinv[v] = rsqrtf((float)degi[v] + 1.0f);
}

// ---------------------------------------------------------------------------
// Exclusive scan of degi -> row_start (3 passes, unchanged from R2).
__global__ __launch_bounds__(256) void scan_block_sums(const int* __restrict__ degi,
                                                       int* __restrict__ bsum) {
    __shared__ int ls[256];
    int v = blockIdx.x * 256 + threadIdx.x;
    int d = (v < NN) ? degi[v] : 0;
    ls[threadIdx.x] = d;
    __syncthreads();
    for (int off = 128; off > 0; off >>= 1) {
        if (threadIdx.x < off) ls[threadIdx.x] += ls[threadIdx.x + off];
        __syncthreads();
    }
    if (threadIdx.x == 0) bsum[blockIdx.x] = ls[0];
}

__global__ __launch_bounds__(512) void scan_bsums(const int* __restrict__ bsum,
                                                  int* __restrict__ boff) {
    __shared__ int ls[512];
    int tid = threadIdx.x;
    int val = (tid < NBLK) ? bsum[tid] : 0;
    ls[tid] = val;
    __syncthreads();
    for (int off = 1; off < 512; off <<= 1) {
        int t = (tid >= off) ? ls[tid - off] : 0;
        __syncthreads();
        ls[tid] += t;
        __syncthreads();
    }
    if (tid < NBLK) boff[tid] = ls[tid] - val;  // exclusive
}

__global__ __launch_bounds__(256) void scan_final(const int* __restrict__ degi,
                                                  const int* __restrict__ boff,
                                                  int* __restrict__ row_start,
                                                  int* __restrict__ cursor) {
    __shared__ int ls[256];
    int b = blockIdx.x, tid = threadIdx.x;
    int v = b * 256 + tid;
    int d = (v < NN) ? degi[v] : 0;
    ls[tid] = d;
    __syncthreads();
    for (int off = 1; off < 256; off <<= 1) {
        int t = (tid >= off) ? ls[tid - off] : 0;
        __syncthreads();
        ls[tid] += t;
        __syncthreads();
    }
    int rs = boff[b] + ls[tid] - d;  // exclusive
    if (v < NN) { row_start[v] = rs; cursor[v] = rs; }
    if (b == 0 && tid == 0) row_start[NN] = NE;
}

// ---------------------------------------------------------------------------
// Partitioned placement with wave queue: csr_src[cursor[dst]++] = src.
// Bucketed by dst range so each csr/cursor line is written by one XCD.
__global__ __launch_bounds__(256) void place_part(const int* __restrict__ ei,
                                                  int* __restrict__ cursor,
                                                  int* __restrict__ csr_src) {
    __shared__ int Qd[4][128];
    __shared__ int Qs[4][128];
    int lane = threadIdx.x & 63, wave = threadIdx.x >> 6;
    int B = blockIdx.x & (NBUCK - 1);
    int gw = (blockIdx.x >> 4) * 4 + wave;
    const int NW  = NCHUNK * 4;
    const int per = (NE + NW - 1) / NW;
    int e0 = gw * per;
    int e1 = e0 + per; if (e1 > NE) e1 = NE;
    int qn = 0;
    for (int e = e0 + lane; e - lane < e1; e += 64) {
        bool keep = false; int d = 0, s = 0;
        if (e < e1) {
            d = ei[NE + e];
            keep = (bucket_of(d) == B);
            if (keep) s = ei[e];
        }
        unsigned long long m = __ballot(keep);
        if (keep) {
            int rank = __popcll(m & ((1ull << lane) - 1ull));
            Qd[wave][qn + rank] = d;
            Qs[wave][qn + rank] = s;
        }
        qn += __popcll(m);
        if (qn >= 64) {
            int dd = Qd[wave][lane];
            int ss = Qs[wave][lane];
            int pos = atomicAdd(&cursor[dd], 1);
            csr_src[pos] = ss;
            qn -= 64;
            int mvd = (lane < qn) ? Qd[wave][64 + lane] : 0;
            int mvs = (lane < qn) ? Qs[wave][64 + lane] : 0;
            if (lane < qn) { Qd[wave][lane] = mvd; Qs[wave][lane] = mvs; }
        }
    }
    if (lane < qn) {
        int pos = atomicAdd(&cursor[Qd[wave][lane]], 1);
        csr_src[pos] = Qs[wave][lane];
    }
}

// ---------------------------------------------------------------------------
// c0[l][j] = sum_k bs[l][k] * Ws[l+1][j][k]   (bias-fold constants, layers 1,2)
__global__ __launch_bounds__(128) void c0_kernel(const float* __restrict__ Ws,
                                                 const float* __restrict__ bs,
                                                 float* __restrict__ c0) {
    int t = threadIdx.x;
    if (t < 128) {
        int l = t >> 6, j = t & 63;
        const float* Wl = Ws + (size_t)(l + 1) * 4096;
        const float* bl = bs + l * 64;
        float s = 0.0f;
        for (int k = 0; k < 64; ++k) s += bl[k] * Wl[j * 64 + k];
        c0[t] = s;
    }
}

// ---------------------------------------------------------------------------
// bf16 MFMA transform: Gb[v][:] = bf16( scale(v) * (A[v][:] @ W^T) + dv*c0[:] )
// L0=1: A = x (fp32), scale = dinv, no bias term.
// L0=0: A = ACCb (bf16), scale = dinv^2, + dinv*c0 (previous finalize folded).
// One wave per 16-row tile. mfma_f32_16x16x32_bf16:
//   A: lane holds A[m=lane&15][k=quad*8 .. +7]; B: B[k=quad*8..+7][n=lane&15];
//   C/D: (m=quad*4+reg, n=lane&15)  [m89-verified layouts]
template <int L0>
__global__ __launch_bounds__(256) void gemm_mfma(const void* __restrict__ Xin,
                                                 const float* __restrict__ W,
                                                 const float* __restrict__ dinv,
                                                 const float* __restrict__ c0,
                                                 unsigned short* __restrict__ Gb) {
    int lane = threadIdx.x & 63;
    int n16 = lane & 15, quad = lane >> 4;

    // B fragments (held in regs whole kernel): W^T[k][n] = W[n][k]
    s16x8 bfrag[4][2];
#pragma unroll
    for (int t = 0; t < 4; ++t)
#pragma unroll
        for (int c = 0; c < 2; ++c) {
            const float4* wp = (const float4*)(W + (t * 16 + n16) * 64 + c * 32 + quad * 8);
            float4 w0 = wp[0], w1 = wp[1];
            s16x8 f;
            f[0] = f2b(w0.x); f[1] = f2b(w0.y); f[2] = f2b(w0.z); f[3] = f2b(w0.w);
            f[4] = f2b(w1.x); f[5] = f2b(w1.y); f[6] = f2b(w1.z); f[7] = f2b(w1.w);
            bfrag[t][c] = f;
        }

    int wid = (blockIdx.x * blockDim.x + threadIdx.x) >> 6;
    int nw  = (gridDim.x * blockDim.x) >> 6;
    for (int tile = wid; tile < NN / 16; tile += nw) {
        int r0 = tile * 16;
        int m  = r0 + n16;
        s16x8 a[2];
#pragma unroll
        for (int c = 0; c < 2; ++c) {
            if (L0) {
                const float4* xp = (const float4*)((const float*)Xin + (size_t)m * 64 + c * 32 + quad * 8);
                float4 x0 = xp[0], x1 = xp[1];
                s16x8 f;
                f[0] = f2b(x0.x); f[1] = f2b(x0.y); f[2] = f2b(x0.z); f[3] = f2b(x0.w);
                f[4] = f2b(x1.x); f[5] = f2b(x1.y); f[6] = f2b(x1.z); f[7] = f2b(x1.w);
                a[c] = f;
            } else {
                a[c] = *(const s16x8*)((const unsigned short*)Xin + (size_t)m * 64 + c * 32 + quad * 8);
            }
        }
        f32x4 acc[4] = {{0,0,0,0},{0,0,0,0},{0,0,0,0},{0,0,0,0}};
#pragma unroll
        for (int c = 0; c < 2; ++c)
#pragma unroll
            for (int t = 0; t < 4; ++t)
                acc[t] = __builtin_amdgcn_mfma_f32_16x16x32_bf16(a[c], bfrag[t][c], acc[t], 0, 0, 0);

        float dvr[4];
#pragma unroll
        for (int r = 0; r < 4; ++r) dvr[r] = dinv[r0 + quad * 4 + r];
#pragma unroll
        for (int t = 0; t < 4; ++t) {
            float cc = L0 ? 0.0f : c0[t * 16 + n16];
#pragma unroll
            for (int r = 0; r < 4; ++r) {
                float dv = dvr[r];
                float g  = L0 ? dv * acc[t][r] : dv * dv * acc[t][r] + dv * cc;
                Gb[(size_t)(r0 + quad * 4 + r) * 64 + t * 16 + n16] = (unsigned short)f2b(g);
            }
        }
    }
}

// ---------------------------------------------------------------------------
// Atomic-free bf16 aggregation: ACCb[v] = bf16( Gb[v] + sum_in-edges Gb[src] )
__global__ __launch_bounds__(256) void gather_b(const int* __restrict__ row_start,
                                                const int* __restrict__ csr_src,
                                                const unsigned short* __restrict__ Gb,
                                                unsigned short* __restrict__ ACCb) {
    int lane = threadIdx.x & 63;
    int wid  = (blockIdx.x * blockDim.x + threadIdx.x) >> 6;
    int nw   = (gridDim.x * blockDim.x) >> 6;
    for (int v = wid; v < NN; v += nw) {
        int rs = row_start[v];
        int re = row_start[v + 1];
        float acc = b2f(Gb[(size_t)v * 64 + lane]);  // self-loop
        for (int base = rs; base < re; base += 64) {
            int n = re - base;
            if (n > 64) n = 64;
            int myidx = (lane < n) ? csr_src[base + lane] : 0;
#pragma unroll 4
            for (int t = 0; t < n; ++t) {
                int s = __shfl(myidx, t, 64);
                acc += b2f(Gb[(size_t)s * 64 + lane]);
            }
        }
        ACCb[(size_t)v * 64 + lane] = (unsigned short)f2b(acc);
    }
}

// ---------------------------------------------------------------------------
// Column-wise sum / sum-of-squares of y = dinv[v]*ACC[v][j] + blast[j]
__global__ __launch_bounds__(256) void bn_stats(const unsigned short* __restrict__ ACCb,
                                                const float* __restrict__ dinv,
                                                const float* __restrict__ blast,
                                                float* __restrict__ sums) {
    int j = threadIdx.x & 63;
    float b = blast[j];
    int wid = (blockIdx.x * blockDim.x + threadIdx.x) >> 6;
    int nw  = (gridDim.x * blockDim.x) >> 6;
    float s = 0.0f, s2 = 0.0f;
    for (int v = wid; v < NN; v += nw) {
        float y = dinv[v] * b2f(ACCb[(size_t)v * 64 + j]) + b;
        s += y;
        s2 += y * y;
    }
    __shared__ float ls[256], ls2[256];
    ls[threadIdx.x] = s;
    ls2[threadIdx.x] = s2;
    __syncthreads();
    if (threadIdx.x < 64) {
        s  = ls[threadIdx.x] + ls[threadIdx.x + 64] + ls[threadIdx.x + 128] + ls[threadIdx.x + 192];
        s2 = ls2[threadIdx.x] + ls2[threadIdx.x + 64] + ls2[threadIdx.x + 128] + ls2[threadIdx.x + 192];
        atomicAdd(&sums[j], s);
        atomicAdd(&sums[64 + j], s2);
    }
}

__global__ __launch_bounds__(256) void bn_apply(const unsigned short* __restrict__ ACCb,
                                                const float* __restrict__ dinv,
                                                const float* __restrict__ blast,
                                                const float* __restrict__ sums,
                                                const float* __restrict__ gamma,
                                                const float* __restrict__ beta,
                                                float* __restrict__ out) {
    const float invN = 1.0f / (float)NN;
    int stride = gridDim.x * blockDim.x;
    for (int i = blockIdx.x * blockDim.x + threadIdx.x; i < NN * 64; i += stride) {
        int j = i & 63;
        int v = i >> 6;
        float mean = sums[j] * invN;
        float var  = sums[64 + j] * invN - mean * mean;
        float y = dinv[v] * b2f(ACCb[i]) + blast[j];
        out[i] = (y - mean) * rsqrtf(var + BN_EPS) * gamma[j] + beta[j];
    }
}

// ---------------------------------------------------------------------------
extern "C" void kernel_launch(void* const* d_in, const int* in_sizes, int n_in,
                              void* d_out, int out_size, void* d_ws, size_t ws_size,
                              hipStream_t stream) {
    const float* x     = (const float*)d_in[0];
    const int*   ei    = (const int*)d_in[1];
    const float* Ws    = (const float*)d_in[2];
    const float* bs    = (const float*)d_in[3];
    const float* gamma = (const float*)d_in[4];
    const float* beta  = (const float*)d_in[5];
    float* out = (float*)d_out;

    char* ws = (char*)d_ws;
    size_t off = 0;
    unsigned short* ACCb = (unsigned short*)(ws + off); off += (size_t)NN * 64 * 2;
    unsigned short* Gb   = (unsigned short*)(ws + off); off += (size_t)NN * 64 * 2;
    float* dinv      = (float*)(ws + off); off += (size_t)NN * 4;
    float* sums      = (float*)(ws + off); off += 128 * 4;
    float* c0        = (float*)(ws + off); off += 128 * 4;
    int*   degi      = (int*)(ws + off);   off += (size_t)NN * 4;
    int*   row_start = (int*)(ws + off);   off += (size_t)(NN + 1) * 4;
    int*   cursor    = (int*)(ws + off);   off += (size_t)NN * 4;
    int*   bsum      = (int*)(ws + off);   off += 512 * 4;
    int*   boff      = (int*)(ws + off);   off += 512 * 4;
    int*   csr_src   = (int*)(ws + off);   off += (size_t)NE * 4;

    hipMemsetAsync(degi, 0, NN * sizeof(int), stream);
    hipMemsetAsync(sums, 0, 128 * sizeof(float), stream);

    // --- CSR build (XCD-partitioned) ---
    deg_part<<<NBUCK * NCHUNK, 256, 0, stream>>>(ei, degi);
    dinv_kernel<<<(NN + 255) / 256, 256, 0, stream>>>(degi, dinv);
    scan_block_sums<<<NBLK, 256, 0, stream>>>(degi, bsum);
    scan_bsums<<<1, 512, 0, stream>>>(bsum, boff);
    scan_final<<<NBLK, 256, 0, stream>>>(degi, boff, row_start, cursor);
    place_part<<<NBUCK * NCHUNK, 256, 0, stream>>>(ei, cursor, csr_src);
    c0_kernel<<<1, 128, 0, stream>>>(Ws, bs, c0);

    // --- 3 GCN layers: MFMA transform (bf16), then atomic-free gather ---
    gemm_mfma<1><<<1563, 256, 0, stream>>>(x, Ws, dinv, nullptr, Gb);
    gather_b<<<2048, 256, 0, stream>>>(row_start, csr_src, Gb, ACCb);
    for (int l = 1; l < 3; ++l) {
        gemm_mfma<0><<<1563, 256, 0, stream>>>(ACCb, Ws + (size_t)l * 4096, dinv,
                                               c0 + (l - 1) * 64, Gb);
        gather_b<<<2048, 256, 0, stream>>>(row_start, csr_src, Gb, ACCb);
    }

    // --- BatchNorm over nodes ---
    bn_stats<<<2048, 256, 0, stream>>>(ACCb, dinv, bs + 128, sums);
    bn_apply<<<2048, 256, 0, stream>>>(ACCb, dinv, bs + 128, sums, gamma, beta, out);
}